// Round 1
// baseline (577.962 us; speedup 1.0000x reference)
//
#include <hip/hip_runtime.h>

#define N_NODES 500000
typedef unsigned int u32;
typedef unsigned short u16;

// ===========================================================================
// R10: batched-MLP gather kernels.
// rocprof (R9): k_layer2 177us, HBM 5%, VALU 1.2%, occ 56%, VGPR 12 ->
// pure latency/MLP bound (~4 outstanding gathers/wave). Fix: each thread
// batch-loads all 8 of its v4u rec records, then issues all 32 random
// gathers back-to-back, then drains into LDS atomics. ~32 outstanding
// loads/wave (VGPR ~80-115, occupancy tier halves -> net ~3-5x MLP).
//   rec = dl9<<19 | src19   per 512-node dst bucket.
// ===========================================================================
#define NPB    512
#define NBUCK  ((N_NODES + NPB - 1) / NPB)   // 977
#define CAP    20480          // region capacity; E[fill]=16384, sigma~128 (32σ)
#define CH     8192           // edges per scatter chunk/WG
#define EPT    8              // edges per thread in scatter (CH / 1024)
#define STB    1024           // scatter block
#define LTB    512            // layer/deg block
#define SRC19  0x7FFFFu

typedef unsigned int v4u __attribute__((ext_vector_type(4)));
__device__ inline int  nt1i(const int* p) { return __builtin_nontemporal_load(p); }
__device__ inline u32  nt1u(const u32* p) { return __builtin_nontemporal_load(p); }
__device__ inline v4u  nt4u(const u32* p) { return __builtin_nontemporal_load((const v4u*)p); }

// ---- fused scatter: edges register-cached; LDS histogram + scan + presort;
//      coalesced run writes into fixed bucket regions.
__global__ __launch_bounds__(STB) void k_scatter_fused(
        const int* __restrict__ src, const int* __restrict__ dst, int E,
        u32* __restrict__ cur_g, u32* __restrict__ rec) {
    __shared__ u32 srec[CH];        // 32 KB
    __shared__ u16 sbk[CH];         // 16 KB
    __shared__ u32 hist[NBUCK];     // 3.9 KB
    __shared__ u32 sc[1024];        // 4 KB
    __shared__ u32 scn_ex[NBUCK];
    __shared__ u32 cur2[NBUCK];
    __shared__ u32 gbase[NBUCK];
    int tid = threadIdx.x, bid = blockIdx.x;
    for (int b = tid; b < NBUCK; b += STB) hist[b] = 0;
    __syncthreads();
    int e0 = bid * CH, e1 = min(E, e0 + CH), n = e1 - e0;
    // load edges into registers (coalesced), histogram
    u32 dv[EPT], sv[EPT];
#pragma unroll
    for (int k = 0; k < EPT; ++k) {
        int e = e0 + (k << 10) + tid;
        if (e < e1) {
            dv[k] = (u32)nt1i(dst + e);
            sv[k] = (u32)nt1i(src + e);
            atomicAdd(&hist[dv[k] >> 9], 1u);
        }
    }
    __syncthreads();
    // scan over 1024 slots (Hillis-Steele)
    sc[tid] = (tid < NBUCK) ? hist[tid] : 0u;
    __syncthreads();
    for (int off = 1; off < 1024; off <<= 1) {
        u32 t = (tid >= off) ? sc[tid - off] : 0u;
        __syncthreads();
        sc[tid] += t;
        __syncthreads();
    }
    if (tid < NBUCK) {
        u32 ex = sc[tid] - hist[tid];
        scn_ex[tid] = ex;
        cur2[tid] = ex;
        gbase[tid] = hist[tid] ? atomicAdd(&cur_g[tid], hist[tid]) : 0u;
    }
    __syncthreads();
    // presort into LDS from registers
#pragma unroll
    for (int k = 0; k < EPT; ++k) {
        int e = e0 + (k << 10) + tid;
        if (e < e1) {
            u32 b = dv[k] >> 9;
            u32 p = atomicAdd(&cur2[b], 1u);
            srec[p] = ((dv[k] & (NPB - 1u)) << 19) | sv[k];
            sbk[p] = (u16)b;
        }
    }
    __syncthreads();
    // coalesced run writes into bucket regions
    for (int p = tid; p < n; p += STB) {
        u32 b = sbk[p];
        u32 slot = gbase[b] + ((u32)p - scn_ex[b]);
        rec[(size_t)b * CAP + slot] = srec[p];
    }
}

// ---- per-bucket degree -> dis = rsqrt(deg+1), m1 = dis*x
//      batched rec loads (8 in flight) to keep the stream saturated.
__global__ __launch_bounds__(LTB) void k_deg_dis(
        const u32* __restrict__ rec, const u32* __restrict__ cnt_g,
        const float* __restrict__ x,
        float* __restrict__ dis, float* __restrict__ m1) {
    __shared__ u32 cnt[NPB];
    int tid = threadIdx.x, bid = blockIdx.x;
    for (int l = tid; l < NPB; l += LTB) cnt[l] = 0;
    __syncthreads();
    const u32* r0 = rec + (size_t)bid * CAP;
    u32 n = cnt_g[bid];
    u32 nv = n >> 2;
    u32 i = tid;
    for (; i + 7u * LTB < nv; i += 8u * LTB) {
        v4u r[8];
#pragma unroll
        for (int k = 0; k < 8; ++k) r[k] = nt4u(r0 + ((size_t)(i + (u32)k * LTB) << 2));
#pragma unroll
        for (int k = 0; k < 8; ++k) {
            atomicAdd(&cnt[r[k].x >> 19], 1u);
            atomicAdd(&cnt[r[k].y >> 19], 1u);
            atomicAdd(&cnt[r[k].z >> 19], 1u);
            atomicAdd(&cnt[r[k].w >> 19], 1u);
        }
    }
    for (; i < nv; i += LTB) {
        v4u r = nt4u(r0 + ((size_t)i << 2));
        atomicAdd(&cnt[r.x >> 19], 1u);
        atomicAdd(&cnt[r.y >> 19], 1u);
        atomicAdd(&cnt[r.z >> 19], 1u);
        atomicAdd(&cnt[r.w >> 19], 1u);
    }
    for (u32 e = (nv << 2) + tid; e < n; e += LTB)
        atomicAdd(&cnt[nt1u(r0 + e) >> 19], 1u);
    __syncthreads();
    int node0 = bid << 9;
    int nn = min(NPB, N_NODES - node0);
    for (int l = tid; l < nn; l += LTB) {
        int node = node0 + l;
        float r = rsqrtf((float)(cnt[l] + 1u));   // +1 self-loop; always > 0
        dis[node] = r;
        m1[node] = r * x[node];
    }
}

// ---- layer-1: gather m1[src] + LDS acc; then per-node MLP -> h2m, out
//      batch-8: 8 rec vectors then 32 gathers in flight before any atomic.
__global__ __launch_bounds__(LTB) void k_layer1(
        const u32* __restrict__ rec, const u32* __restrict__ cnt_g,
        const float* __restrict__ dis, const float* __restrict__ m1,
        const float* __restrict__ W1, const float* __restrict__ b1,
        const float* __restrict__ W2, const float* __restrict__ b2,
        float2* __restrict__ h2m, float2* __restrict__ out) {
    __shared__ float acc[NPB];
    int tid = threadIdx.x, bid = blockIdx.x;
    for (int l = tid; l < NPB; l += LTB) acc[l] = 0.f;
    __syncthreads();
    const u32* r0 = rec + (size_t)bid * CAP;
    u32 n = cnt_g[bid];
    u32 nv = n >> 2;
    u32 i = tid;
    for (; i + 7u * LTB < nv; i += 8u * LTB) {
        v4u r[8];
#pragma unroll
        for (int k = 0; k < 8; ++k) r[k] = nt4u(r0 + ((size_t)(i + (u32)k * LTB) << 2));
        float v[8][4];
#pragma unroll
        for (int k = 0; k < 8; ++k) {
            v[k][0] = m1[r[k].x & SRC19];
            v[k][1] = m1[r[k].y & SRC19];
            v[k][2] = m1[r[k].z & SRC19];
            v[k][3] = m1[r[k].w & SRC19];
        }
#pragma unroll
        for (int k = 0; k < 8; ++k) {
            atomicAdd(&acc[r[k].x >> 19], v[k][0]);
            atomicAdd(&acc[r[k].y >> 19], v[k][1]);
            atomicAdd(&acc[r[k].z >> 19], v[k][2]);
            atomicAdd(&acc[r[k].w >> 19], v[k][3]);
        }
    }
    for (; i < nv; i += LTB) {
        v4u r = nt4u(r0 + ((size_t)i << 2));
        float v0 = m1[r.x & SRC19];
        float v1 = m1[r.y & SRC19];
        float v2 = m1[r.z & SRC19];
        float v3 = m1[r.w & SRC19];
        atomicAdd(&acc[r.x >> 19], v0);
        atomicAdd(&acc[r.y >> 19], v1);
        atomicAdd(&acc[r.z >> 19], v2);
        atomicAdd(&acc[r.w >> 19], v3);
    }
    for (u32 e = (nv << 2) + tid; e < n; e += LTB) {
        u32 r = nt1u(r0 + e);
        atomicAdd(&acc[r >> 19], m1[r & SRC19]);
    }
    __syncthreads();
    int node0 = bid << 9;
    int nn = min(NPB, N_NODES - node0);
    for (int l = tid; l < nn; l += LTB) {
        int node = node0 + l;
        float d = dis[node];
        float s = d * (acc[l] + m1[node]);
        float a0 = 0.f, a1 = 0.f;
#pragma unroll
        for (int k = 0; k < 8; ++k) {
            float h = fmaxf(W1[k] * s + b1[k], 0.f);
            a0 += h * W2[2 * k + 0];
            a1 += h * W2[2 * k + 1];
        }
        h2m[node] = make_float2(d * a0, d * a1);                    // dis[src]*h2
        out[node] = make_float2(b2[0] + d * d * a0, b2[1] + d * d * a1);
    }
}

// ---- layer-2: gather h2m[src] + two LDS planes; out += dis*sum
//      batch-8: 8 rec vectors then 32 float2 gathers in flight.
__global__ __launch_bounds__(LTB) void k_layer2(
        const u32* __restrict__ rec, const u32* __restrict__ cnt_g,
        const float* __restrict__ dis, const float2* __restrict__ h2m,
        float2* __restrict__ out) {
    __shared__ float ax[NPB];
    __shared__ float ay[NPB];
    int tid = threadIdx.x, bid = blockIdx.x;
    for (int l = tid; l < NPB; l += LTB) { ax[l] = 0.f; ay[l] = 0.f; }
    __syncthreads();
    const u32* r0 = rec + (size_t)bid * CAP;
    u32 n = cnt_g[bid];
    u32 nv = n >> 2;
    u32 i = tid;
    for (; i + 7u * LTB < nv; i += 8u * LTB) {
        v4u r[8];
#pragma unroll
        for (int k = 0; k < 8; ++k) r[k] = nt4u(r0 + ((size_t)(i + (u32)k * LTB) << 2));
        float2 v[8][4];
#pragma unroll
        for (int k = 0; k < 8; ++k) {
            v[k][0] = h2m[r[k].x & SRC19];
            v[k][1] = h2m[r[k].y & SRC19];
            v[k][2] = h2m[r[k].z & SRC19];
            v[k][3] = h2m[r[k].w & SRC19];
        }
#pragma unroll
        for (int k = 0; k < 8; ++k) {
            atomicAdd(&ax[r[k].x >> 19], v[k][0].x);
            atomicAdd(&ay[r[k].x >> 19], v[k][0].y);
            atomicAdd(&ax[r[k].y >> 19], v[k][1].x);
            atomicAdd(&ay[r[k].y >> 19], v[k][1].y);
            atomicAdd(&ax[r[k].z >> 19], v[k][2].x);
            atomicAdd(&ay[r[k].z >> 19], v[k][2].y);
            atomicAdd(&ax[r[k].w >> 19], v[k][3].x);
            atomicAdd(&ay[r[k].w >> 19], v[k][3].y);
        }
    }
    for (; i < nv; i += LTB) {
        v4u r = nt4u(r0 + ((size_t)i << 2));
        float2 v0 = h2m[r.x & SRC19];
        float2 v1 = h2m[r.y & SRC19];
        float2 v2 = h2m[r.z & SRC19];
        float2 v3 = h2m[r.w & SRC19];
        atomicAdd(&ax[r.x >> 19], v0.x);
        atomicAdd(&ay[r.x >> 19], v0.y);
        atomicAdd(&ax[r.y >> 19], v1.x);
        atomicAdd(&ay[r.y >> 19], v1.y);
        atomicAdd(&ax[r.z >> 19], v2.x);
        atomicAdd(&ay[r.z >> 19], v2.y);
        atomicAdd(&ax[r.w >> 19], v3.x);
        atomicAdd(&ay[r.w >> 19], v3.y);
    }
    for (u32 e = (nv << 2) + tid; e < n; e += LTB) {
        u32 r = nt1u(r0 + e);
        float2 v = h2m[r & SRC19];
        atomicAdd(&ax[r >> 19], v.x);
        atomicAdd(&ay[r >> 19], v.y);
    }
    __syncthreads();
    int node0 = bid << 9;
    int nn = min(NPB, N_NODES - node0);
    for (int l = tid; l < nn; l += LTB) {
        int node = node0 + l;
        float d = dis[node];
        float2 o = out[node];
        out[node] = make_float2(o.x + d * ax[l], o.y + d * ay[l]);
    }
}

// ===========================================================================
// Fallback path (R1): global atomics — only if ws too small (needs 10 MB).
// ===========================================================================
__global__ void f_count_deg(const int* __restrict__ dst, int E,
                            u32* __restrict__ deg) {
    int i = blockIdx.x * blockDim.x + threadIdx.x;
    int stride = gridDim.x * blockDim.x;
    for (int e = i; e < E; e += stride) atomicAdd(&deg[dst[e]], 1u);
}
__global__ void f_dis_sinit(const u32* __restrict__ deg, const float* __restrict__ x,
                            float* __restrict__ dis, float* __restrict__ s, int N) {
    int i = blockIdx.x * blockDim.x + threadIdx.x;
    if (i < N) {
        float r = rsqrtf((float)(deg[i] + 1u));
        dis[i] = r;
        s[i] = r * r * x[i];
    }
}
__global__ void f_agg1(const int* __restrict__ src, const int* __restrict__ dst,
                       int E, const float* __restrict__ dis,
                       const float* __restrict__ x, float* __restrict__ s) {
    int i = blockIdx.x * blockDim.x + threadIdx.x;
    int stride = gridDim.x * blockDim.x;
    for (int e = i; e < E; e += stride) {
        int sj = src[e], dj = dst[e];
        atomicAdd(&s[dj], dis[sj] * dis[dj] * x[sj]);
    }
}
__global__ void f_node2(const float* __restrict__ s, const float* __restrict__ dis,
                        const float* __restrict__ W1, const float* __restrict__ b1,
                        const float* __restrict__ W2, const float* __restrict__ b2,
                        float2* __restrict__ h2, float2* __restrict__ out, int N) {
    int i = blockIdx.x * blockDim.x + threadIdx.x;
    if (i >= N) return;
    float si = s[i];
    float a0 = 0.f, a1 = 0.f;
#pragma unroll
    for (int k = 0; k < 8; ++k) {
        float hk = fmaxf(W1[k] * si + b1[k], 0.f);
        a0 += hk * W2[2 * k + 0];
        a1 += hk * W2[2 * k + 1];
    }
    h2[i] = make_float2(a0, a1);
    float r2 = dis[i] * dis[i];
    out[i] = make_float2(b2[0] + r2 * a0, b2[1] + r2 * a1);
}
__global__ void f_agg2(const int* __restrict__ src, const int* __restrict__ dst,
                       int E, const float* __restrict__ dis,
                       const float2* __restrict__ h2, float* __restrict__ out) {
    int i = blockIdx.x * blockDim.x + threadIdx.x;
    int stride = gridDim.x * blockDim.x;
    for (int e = i; e < E; e += stride) {
        int sj = src[e], dj = dst[e];
        float nm = dis[sj] * dis[dj];
        float2 v = h2[sj];
        atomicAdd(&out[2 * dj + 0], nm * v.x);
        atomicAdd(&out[2 * dj + 1], nm * v.y);
    }
}

// ===========================================================================
extern "C" void kernel_launch(void* const* d_in, const int* in_sizes, int n_in,
                              void* d_out, int out_size, void* d_ws, size_t ws_size,
                              hipStream_t stream) {
    const float* x  = (const float*)d_in[0];
    const int*   ei = (const int*)d_in[1];   // [2,E]: src row, then dst row
    const float* W1 = (const float*)d_in[2];
    const float* b1 = (const float*)d_in[3];
    const float* W2 = (const float*)d_in[4];
    const float* b2 = (const float*)d_in[5];

    const int N = N_NODES;
    const int E = in_sizes[1] / 2;
    const int* src = ei;
    const int* dst = ei + E;
    float* out = (float*)d_out;
    char* ws = (char*)d_ws;

    // ---- fast-path workspace ----
    size_t off = 0;
    auto take = [&](size_t bytes) { size_t o = off; off = (off + bytes + 255) & ~(size_t)255; return o; };
    size_t off_cur  = take(NBUCK * 4);
    size_t off_dis  = take((size_t)N * 4);
    size_t off_m1   = take((size_t)N * 4);
    size_t off_h2m  = take((size_t)N * 8);
    size_t off_rec  = take((size_t)NBUCK * CAP * 4 + 16);   // ~80 MB
    size_t need     = off;

    if (ws_size >= need) {
        u32* cur_g  = (u32*)(ws + off_cur);
        float* dis  = (float*)(ws + off_dis);
        float* m1   = (float*)(ws + off_m1);
        float2* h2m = (float2*)(ws + off_h2m);
        u32* rec    = (u32*)(ws + off_rec);

        hipMemsetAsync(cur_g, 0, NBUCK * 4, stream);
        const int nchunks = (E + CH - 1) / CH;
        k_scatter_fused<<<nchunks, STB, 0, stream>>>(src, dst, E, cur_g, rec);
        k_deg_dis      <<<NBUCK,   LTB, 0, stream>>>(rec, cur_g, x, dis, m1);
        k_layer1       <<<NBUCK,   LTB, 0, stream>>>(rec, cur_g, dis, m1,
                                                     W1, b1, W2, b2,
                                                     h2m, (float2*)out);
        k_layer2       <<<NBUCK,   LTB, 0, stream>>>(rec, cur_g, dis, h2m,
                                                     (float2*)out);
        return;
    }

    // ---- fallback: R1 global-atomic path (10 MB ws) ----
    u32* deg    = (u32*)(ws);
    float* dis  = (float*)(ws + (size_t)N * 4);
    float* s    = (float*)(ws + (size_t)N * 8);
    float2* h2  = (float2*)(ws + (size_t)N * 12);
    hipMemsetAsync(deg, 0, (size_t)N * 4, stream);
    int nodeBlocks = (N + 255) / 256;
    int edgeBlocks = (E + 255) / 256;
    f_count_deg<<<edgeBlocks, 256, 0, stream>>>(dst, E, deg);
    f_dis_sinit<<<nodeBlocks, 256, 0, stream>>>(deg, x, dis, s, N);
    f_agg1     <<<edgeBlocks, 256, 0, stream>>>(src, dst, E, dis, x, s);
    f_node2    <<<nodeBlocks, 256, 0, stream>>>(s, dis, W1, b1, W2, b2, h2,
                                                (float2*)out, N);
    f_agg2     <<<edgeBlocks, 256, 0, stream>>>(src, dst, E, dis, h2, out);
}

// Round 4
// 519.335 us; speedup vs baseline: 1.1129x; 1.1129x over previous
//
#include <hip/hip_runtime.h>

#define N_NODES 500000
typedef unsigned int u32;
typedef unsigned short u16;

// ===========================================================================
// R13 = R12 resubmitted verbatim (R12 never ran: MI355X container failed
// twice — infra, not kernel). Explicit 2-slot software pipeline in the
// gather layers; macro-pasting fix ((g##0).x) applied.
// R10 post-mortem: batch-8 arrays were de-pipelined by the compiler
// (VGPR=52 proves gathers never batched in-flight) -> latency theory
// untested. Pin the schedule with named registers + sched_barrier(0):
//   ITER(k): prefetch rec(k+2) | issue 4 gathers of batch k+1 | fence |
//            drain batch k's LDS atomics.
// ~5-9 vmem in flight/wave x 30 resident waves/CU. VGPR ~45 keeps 8 w/SIMD.
//   rec = dl9<<19 | src19   per 512-node dst bucket.
// ===========================================================================
#define NPB    512
#define NBUCK  ((N_NODES + NPB - 1) / NPB)   // 977
#define CAP    20480          // region capacity; E[fill]=16384, sigma~128 (32σ)
#define CH     8192           // edges per scatter chunk/WG
#define EPT    8              // edges per thread in scatter (CH / 1024)
#define STB    1024           // scatter block
#define LTB    512            // layer/deg block
#define SRC19  0x7FFFFu

typedef unsigned int v4u __attribute__((ext_vector_type(4)));
__device__ inline int  nt1i(const int* p) { return __builtin_nontemporal_load(p); }
__device__ inline u32  nt1u(const u32* p) { return __builtin_nontemporal_load(p); }
__device__ inline v4u  nt4u(const u32* p) { return __builtin_nontemporal_load((const v4u*)p); }

// ---- fused scatter: edges register-cached; LDS histogram + scan + presort;
//      coalesced run writes into fixed bucket regions.
__global__ __launch_bounds__(STB) void k_scatter_fused(
        const int* __restrict__ src, const int* __restrict__ dst, int E,
        u32* __restrict__ cur_g, u32* __restrict__ rec) {
    __shared__ u32 srec[CH];        // 32 KB
    __shared__ u16 sbk[CH];         // 16 KB
    __shared__ u32 hist[NBUCK];     // 3.9 KB
    __shared__ u32 sc[1024];        // 4 KB
    __shared__ u32 scn_ex[NBUCK];
    __shared__ u32 cur2[NBUCK];
    __shared__ u32 gbase[NBUCK];
    int tid = threadIdx.x, bid = blockIdx.x;
    for (int b = tid; b < NBUCK; b += STB) hist[b] = 0;
    __syncthreads();
    int e0 = bid * CH, e1 = min(E, e0 + CH), n = e1 - e0;
    // load edges into registers (coalesced), histogram
    u32 dv[EPT], sv[EPT];
#pragma unroll
    for (int k = 0; k < EPT; ++k) {
        int e = e0 + (k << 10) + tid;
        if (e < e1) {
            dv[k] = (u32)nt1i(dst + e);
            sv[k] = (u32)nt1i(src + e);
            atomicAdd(&hist[dv[k] >> 9], 1u);
        }
    }
    __syncthreads();
    // scan over 1024 slots (Hillis-Steele)
    sc[tid] = (tid < NBUCK) ? hist[tid] : 0u;
    __syncthreads();
    for (int off = 1; off < 1024; off <<= 1) {
        u32 t = (tid >= off) ? sc[tid - off] : 0u;
        __syncthreads();
        sc[tid] += t;
        __syncthreads();
    }
    if (tid < NBUCK) {
        u32 ex = sc[tid] - hist[tid];
        scn_ex[tid] = ex;
        cur2[tid] = ex;
        gbase[tid] = hist[tid] ? atomicAdd(&cur_g[tid], hist[tid]) : 0u;
    }
    __syncthreads();
    // presort into LDS from registers
#pragma unroll
    for (int k = 0; k < EPT; ++k) {
        int e = e0 + (k << 10) + tid;
        if (e < e1) {
            u32 b = dv[k] >> 9;
            u32 p = atomicAdd(&cur2[b], 1u);
            srec[p] = ((dv[k] & (NPB - 1u)) << 19) | sv[k];
            sbk[p] = (u16)b;
        }
    }
    __syncthreads();
    // coalesced run writes into bucket regions
    for (int p = tid; p < n; p += STB) {
        u32 b = sbk[p];
        u32 slot = gbase[b] + ((u32)p - scn_ex[b]);
        rec[(size_t)b * CAP + slot] = srec[p];
    }
}

// ---- per-bucket degree -> dis = rsqrt(deg+1), m1 = dis*x  (R9 form)
__global__ __launch_bounds__(LTB) void k_deg_dis(
        const u32* __restrict__ rec, const u32* __restrict__ cnt_g,
        const float* __restrict__ x,
        float* __restrict__ dis, float* __restrict__ m1) {
    __shared__ u32 cnt[NPB];
    int tid = threadIdx.x, bid = blockIdx.x;
    for (int l = tid; l < NPB; l += LTB) cnt[l] = 0;
    __syncthreads();
    const u32* r0 = rec + (size_t)bid * CAP;
    u32 n = cnt_g[bid];
    u32 nv = n >> 2;
    for (u32 i = tid; i < nv; i += LTB) {
        v4u r = nt4u(r0 + ((size_t)i << 2));
        atomicAdd(&cnt[r.x >> 19], 1u);
        atomicAdd(&cnt[r.y >> 19], 1u);
        atomicAdd(&cnt[r.z >> 19], 1u);
        atomicAdd(&cnt[r.w >> 19], 1u);
    }
    for (u32 e = (nv << 2) + tid; e < n; e += LTB)
        atomicAdd(&cnt[nt1u(r0 + e) >> 19], 1u);
    __syncthreads();
    int node0 = bid << 9;
    int nn = min(NPB, N_NODES - node0);
    for (int l = tid; l < nn; l += LTB) {
        int node = node0 + l;
        float r = rsqrtf((float)(cnt[l] + 1u));   // +1 self-loop; always > 0
        dis[node] = r;
        m1[node] = r * x[node];
    }
}

// ======================= layer-1 (float payload) ===========================
#define L1_GATHER(g, r, d)                                     \
    d##0 = (r.x >> 19) | ((r.y >> 19) << 16);                  \
    d##1 = (r.z >> 19) | ((r.w >> 19) << 16);                  \
    g##0 = m1[r.x & SRC19]; g##1 = m1[r.y & SRC19];            \
    g##2 = m1[r.z & SRC19]; g##3 = m1[r.w & SRC19];

#define L1_CONSUME(g, d)                                       \
    atomicAdd(&acc[d##0 & 0xFFFFu], g##0);                     \
    atomicAdd(&acc[d##0 >> 16],     g##1);                     \
    atomicAdd(&acc[d##1 & 0xFFFFu], g##2);                     \
    atomicAdd(&acc[d##1 >> 16],     g##3);

__global__ __launch_bounds__(LTB) void k_layer1(
        const u32* __restrict__ rec, const u32* __restrict__ cnt_g,
        const float* __restrict__ dis, const float* __restrict__ m1,
        const float* __restrict__ W1, const float* __restrict__ b1,
        const float* __restrict__ W2, const float* __restrict__ b2,
        float2* __restrict__ h2m, float2* __restrict__ out) {
    __shared__ float acc[NPB];
    int tid = threadIdx.x, bid = blockIdx.x;
    for (int l = tid; l < NPB; l += LTB) acc[l] = 0.f;
    __syncthreads();
    const u32* r0 = rec + (size_t)bid * CAP;
    u32 n = cnt_g[bid];
    u32 nv = n >> 2;
    u32 nfull = nv / LTB;
    u32 i = tid;

    if (nfull >= 2) {
        u32 dA0, dA1, dB0, dB1;
        float gA0, gA1, gA2, gA3, gB0, gB1, gB2, gB3;
        v4u rA = nt4u(r0 + ((size_t)i << 2));
        v4u rB = nt4u(r0 + (((size_t)i + LTB) << 2));
        L1_GATHER(gA, rA, dA)
        u32 k = 0;
        for (; k + 2 <= nfull - 1; k += 2) {
            rA = nt4u(r0 + (((size_t)i + (k + 2) * LTB) << 2));   // prefetch rec k+2
            L1_GATHER(gB, rB, dB)                                 // gathers batch k+1
            __builtin_amdgcn_sched_barrier(0);
            L1_CONSUME(gA, dA)                                    // drain batch k
            rB = nt4u(r0 + (((size_t)i + (k + 3) * LTB) << 2));   // prefetch rec k+3 (may be garbage; in-bounds, never consumed)
            L1_GATHER(gA, rA, dA)                                 // gathers batch k+2
            __builtin_amdgcn_sched_barrier(0);
            L1_CONSUME(gB, dB)                                    // drain batch k+1
        }
        if (k + 1 <= nfull - 1) {     // one ITER left: issue k+1, drain k, drain k+1
            L1_GATHER(gB, rB, dB)
            __builtin_amdgcn_sched_barrier(0);
            L1_CONSUME(gA, dA)
            L1_CONSUME(gB, dB)
        } else {
            L1_CONSUME(gA, dA)
        }
    }
    // remainder (whole bucket if nfull < 2)
    u32 start = (nfull >= 2) ? nfull * LTB : 0u;
    for (u32 ii = start + tid; ii < nv; ii += LTB) {
        v4u r = nt4u(r0 + ((size_t)ii << 2));
        float v0 = m1[r.x & SRC19];
        float v1 = m1[r.y & SRC19];
        float v2 = m1[r.z & SRC19];
        float v3 = m1[r.w & SRC19];
        atomicAdd(&acc[r.x >> 19], v0);
        atomicAdd(&acc[r.y >> 19], v1);
        atomicAdd(&acc[r.z >> 19], v2);
        atomicAdd(&acc[r.w >> 19], v3);
    }
    for (u32 e = (nv << 2) + tid; e < n; e += LTB) {
        u32 r = nt1u(r0 + e);
        atomicAdd(&acc[r >> 19], m1[r & SRC19]);
    }
    __syncthreads();
    int node0 = bid << 9;
    int nn = min(NPB, N_NODES - node0);
    for (int l = tid; l < nn; l += LTB) {
        int node = node0 + l;
        float d = dis[node];
        float s = d * (acc[l] + m1[node]);
        float a0 = 0.f, a1 = 0.f;
#pragma unroll
        for (int k = 0; k < 8; ++k) {
            float h = fmaxf(W1[k] * s + b1[k], 0.f);
            a0 += h * W2[2 * k + 0];
            a1 += h * W2[2 * k + 1];
        }
        h2m[node] = make_float2(d * a0, d * a1);                    // dis[src]*h2
        out[node] = make_float2(b2[0] + d * d * a0, b2[1] + d * d * a1);
    }
}

// ======================= layer-2 (float2 payload) ==========================
#define L2_GATHER(g, r, d)                                     \
    d##0 = (r.x >> 19) | ((r.y >> 19) << 16);                  \
    d##1 = (r.z >> 19) | ((r.w >> 19) << 16);                  \
    g##0 = h2m[r.x & SRC19]; g##1 = h2m[r.y & SRC19];          \
    g##2 = h2m[r.z & SRC19]; g##3 = h2m[r.w & SRC19];

#define L2_CONSUME(g, d)                                       \
    atomicAdd(&ax[d##0 & 0xFFFFu], (g##0).x);                  \
    atomicAdd(&ay[d##0 & 0xFFFFu], (g##0).y);                  \
    atomicAdd(&ax[d##0 >> 16],     (g##1).x);                  \
    atomicAdd(&ay[d##0 >> 16],     (g##1).y);                  \
    atomicAdd(&ax[d##1 & 0xFFFFu], (g##2).x);                  \
    atomicAdd(&ay[d##1 & 0xFFFFu], (g##2).y);                  \
    atomicAdd(&ax[d##1 >> 16],     (g##3).x);                  \
    atomicAdd(&ay[d##1 >> 16],     (g##3).y);

__global__ __launch_bounds__(LTB) void k_layer2(
        const u32* __restrict__ rec, const u32* __restrict__ cnt_g,
        const float* __restrict__ dis, const float2* __restrict__ h2m,
        float2* __restrict__ out) {
    __shared__ float ax[NPB];
    __shared__ float ay[NPB];
    int tid = threadIdx.x, bid = blockIdx.x;
    for (int l = tid; l < NPB; l += LTB) { ax[l] = 0.f; ay[l] = 0.f; }
    __syncthreads();
    const u32* r0 = rec + (size_t)bid * CAP;
    u32 n = cnt_g[bid];
    u32 nv = n >> 2;
    u32 nfull = nv / LTB;
    u32 i = tid;

    if (nfull >= 2) {
        u32 dA0, dA1, dB0, dB1;
        float2 gA0, gA1, gA2, gA3, gB0, gB1, gB2, gB3;
        v4u rA = nt4u(r0 + ((size_t)i << 2));
        v4u rB = nt4u(r0 + (((size_t)i + LTB) << 2));
        L2_GATHER(gA, rA, dA)
        u32 k = 0;
        for (; k + 2 <= nfull - 1; k += 2) {
            rA = nt4u(r0 + (((size_t)i + (k + 2) * LTB) << 2));   // prefetch rec k+2
            L2_GATHER(gB, rB, dB)                                 // gathers batch k+1
            __builtin_amdgcn_sched_barrier(0);
            L2_CONSUME(gA, dA)                                    // drain batch k
            rB = nt4u(r0 + (((size_t)i + (k + 3) * LTB) << 2));   // prefetch rec k+3 (may be garbage; in-bounds, never consumed)
            L2_GATHER(gA, rA, dA)                                 // gathers batch k+2
            __builtin_amdgcn_sched_barrier(0);
            L2_CONSUME(gB, dB)                                    // drain batch k+1
        }
        if (k + 1 <= nfull - 1) {
            L2_GATHER(gB, rB, dB)
            __builtin_amdgcn_sched_barrier(0);
            L2_CONSUME(gA, dA)
            L2_CONSUME(gB, dB)
        } else {
            L2_CONSUME(gA, dA)
        }
    }
    // remainder (whole bucket if nfull < 2)
    u32 start = (nfull >= 2) ? nfull * LTB : 0u;
    for (u32 ii = start + tid; ii < nv; ii += LTB) {
        v4u r = nt4u(r0 + ((size_t)ii << 2));
        float2 v0 = h2m[r.x & SRC19];
        float2 v1 = h2m[r.y & SRC19];
        float2 v2 = h2m[r.z & SRC19];
        float2 v3 = h2m[r.w & SRC19];
        atomicAdd(&ax[r.x >> 19], v0.x);
        atomicAdd(&ay[r.x >> 19], v0.y);
        atomicAdd(&ax[r.y >> 19], v1.x);
        atomicAdd(&ay[r.y >> 19], v1.y);
        atomicAdd(&ax[r.z >> 19], v2.x);
        atomicAdd(&ay[r.z >> 19], v2.y);
        atomicAdd(&ax[r.w >> 19], v3.x);
        atomicAdd(&ay[r.w >> 19], v3.y);
    }
    for (u32 e = (nv << 2) + tid; e < n; e += LTB) {
        u32 r = nt1u(r0 + e);
        float2 v = h2m[r & SRC19];
        atomicAdd(&ax[r >> 19], v.x);
        atomicAdd(&ay[r >> 19], v.y);
    }
    __syncthreads();
    int node0 = bid << 9;
    int nn = min(NPB, N_NODES - node0);
    for (int l = tid; l < nn; l += LTB) {
        int node = node0 + l;
        float d = dis[node];
        float2 o = out[node];
        out[node] = make_float2(o.x + d * ax[l], o.y + d * ay[l]);
    }
}

// ===========================================================================
// Fallback path (R1): global atomics — only if ws too small (needs 10 MB).
// ===========================================================================
__global__ void f_count_deg(const int* __restrict__ dst, int E,
                            u32* __restrict__ deg) {
    int i = blockIdx.x * blockDim.x + threadIdx.x;
    int stride = gridDim.x * blockDim.x;
    for (int e = i; e < E; e += stride) atomicAdd(&deg[dst[e]], 1u);
}
__global__ void f_dis_sinit(const u32* __restrict__ deg, const float* __restrict__ x,
                            float* __restrict__ dis, float* __restrict__ s, int N) {
    int i = blockIdx.x * blockDim.x + threadIdx.x;
    if (i < N) {
        float r = rsqrtf((float)(deg[i] + 1u));
        dis[i] = r;
        s[i] = r * r * x[i];
    }
}
__global__ void f_agg1(const int* __restrict__ src, const int* __restrict__ dst,
                       int E, const float* __restrict__ dis,
                       const float* __restrict__ x, float* __restrict__ s) {
    int i = blockIdx.x * blockDim.x + threadIdx.x;
    int stride = gridDim.x * blockDim.x;
    for (int e = i; e < E; e += stride) {
        int sj = src[e], dj = dst[e];
        atomicAdd(&s[dj], dis[sj] * dis[dj] * x[sj]);
    }
}
__global__ void f_node2(const float* __restrict__ s, const float* __restrict__ dis,
                        const float* __restrict__ W1, const float* __restrict__ b1,
                        const float* __restrict__ W2, const float* __restrict__ b2,
                        float2* __restrict__ h2, float2* __restrict__ out, int N) {
    int i = blockIdx.x * blockDim.x + threadIdx.x;
    if (i >= N) return;
    float si = s[i];
    float a0 = 0.f, a1 = 0.f;
#pragma unroll
    for (int k = 0; k < 8; ++k) {
        float hk = fmaxf(W1[k] * si + b1[k], 0.f);
        a0 += hk * W2[2 * k + 0];
        a1 += hk * W2[2 * k + 1];
    }
    h2[i] = make_float2(a0, a1);
    float r2 = dis[i] * dis[i];
    out[i] = make_float2(b2[0] + r2 * a0, b2[1] + r2 * a1);
}
__global__ void f_agg2(const int* __restrict__ src, const int* __restrict__ dst,
                       int E, const float* __restrict__ dis,
                       const float2* __restrict__ h2, float* __restrict__ out) {
    int i = blockIdx.x * blockDim.x + threadIdx.x;
    int stride = gridDim.x * blockDim.x;
    for (int e = i; e < E; e += stride) {
        int sj = src[e], dj = dst[e];
        float nm = dis[sj] * dis[dj];
        float2 v = h2[sj];
        atomicAdd(&out[2 * dj + 0], nm * v.x);
        atomicAdd(&out[2 * dj + 1], nm * v.y);
    }
}

// ===========================================================================
extern "C" void kernel_launch(void* const* d_in, const int* in_sizes, int n_in,
                              void* d_out, int out_size, void* d_ws, size_t ws_size,
                              hipStream_t stream) {
    const float* x  = (const float*)d_in[0];
    const int*   ei = (const int*)d_in[1];   // [2,E]: src row, then dst row
    const float* W1 = (const float*)d_in[2];
    const float* b1 = (const float*)d_in[3];
    const float* W2 = (const float*)d_in[4];
    const float* b2 = (const float*)d_in[5];

    const int N = N_NODES;
    const int E = in_sizes[1] / 2;
    const int* src = ei;
    const int* dst = ei + E;
    float* out = (float*)d_out;
    char* ws = (char*)d_ws;

    // ---- fast-path workspace ----
    size_t off = 0;
    auto take = [&](size_t bytes) { size_t o = off; off = (off + bytes + 255) & ~(size_t)255; return o; };
    size_t off_cur  = take(NBUCK * 4);
    size_t off_dis  = take((size_t)N * 4);
    size_t off_m1   = take((size_t)N * 4);
    size_t off_h2m  = take((size_t)N * 8);
    size_t off_rec  = take((size_t)NBUCK * CAP * 4 + 16);   // ~80 MB
    size_t need     = off;

    if (ws_size >= need) {
        u32* cur_g  = (u32*)(ws + off_cur);
        float* dis  = (float*)(ws + off_dis);
        float* m1   = (float*)(ws + off_m1);
        float2* h2m = (float2*)(ws + off_h2m);
        u32* rec    = (u32*)(ws + off_rec);

        hipMemsetAsync(cur_g, 0, NBUCK * 4, stream);
        const int nchunks = (E + CH - 1) / CH;
        k_scatter_fused<<<nchunks, STB, 0, stream>>>(src, dst, E, cur_g, rec);
        k_deg_dis      <<<NBUCK,   LTB, 0, stream>>>(rec, cur_g, x, dis, m1);
        k_layer1       <<<NBUCK,   LTB, 0, stream>>>(rec, cur_g, dis, m1,
                                                     W1, b1, W2, b2,
                                                     h2m, (float2*)out);
        k_layer2       <<<NBUCK,   LTB, 0, stream>>>(rec, cur_g, dis, h2m,
                                                     (float2*)out);
        return;
    }

    // ---- fallback: R1 global-atomic path (10 MB ws) ----
    u32* deg    = (u32*)(ws);
    float* dis  = (float*)(ws + (size_t)N * 4);
    float* s    = (float*)(ws + (size_t)N * 8);
    float2* h2  = (float2*)(ws + (size_t)N * 12);
    hipMemsetAsync(deg, 0, (size_t)N * 4, stream);
    int nodeBlocks = (N + 255) / 256;
    int edgeBlocks = (E + 255) / 256;
    f_count_deg<<<edgeBlocks, 256, 0, stream>>>(dst, E, deg);
    f_dis_sinit<<<nodeBlocks, 256, 0, stream>>>(deg, x, dis, s, N);
    f_agg1     <<<edgeBlocks, 256, 0, stream>>>(src, dst, E, dis, x, s);
    f_node2    <<<nodeBlocks, 256, 0, stream>>>(s, dis, W1, b1, W2, b2, h2,
                                                (float2*)out, N);
    f_agg2     <<<edgeBlocks, 256, 0, stream>>>(src, dst, E, dis, h2, out);
}